// Round 4
// baseline (1892.957 us; speedup 1.0000x reference)
//
#include <hip/hip_runtime.h>

constexpr int LDIM  = 128;
constexpr int NNODE = 20000;
constexpr int EM_N  = 100000;
constexpr int EW_N  = 25000;
constexpr int NSTEP = 6;

typedef short bf16x8 __attribute__((ext_vector_type(8)));
typedef short bf16x4 __attribute__((ext_vector_type(4)));
typedef float f32x4  __attribute__((ext_vector_type(4)));

struct MlpParams {
  const float* x;
  const float* attrIn;
  float*       attrOut;
  const int*   src;
  const int*   dst;
  float*       sum1;    // edge: scatter target; node: mesh sum (zeroed after read)
  float*       sum2;    // node: world sum (zeroed after read)
  const float* inv1;
  const float* inv2;
  const short* W1H;     // bf16 hi [128 n][384 k]
  const short* W1L;
  const short* W2H;     // bf16 hi [128 n][128 k]
  const short* W2L;
  const float* b1;
  const float* b2;
  const float* gam;
  const float* bet;
  int nRows;
};

__device__ __forceinline__ short f2b(float f) {
  unsigned int u = __float_as_uint(f);
  u = (u + 0x7fffu + ((u >> 16) & 1u)) >> 16;
  return (short)u;
}
__device__ __forceinline__ float b2f(short s) {
  return __uint_as_float(((unsigned int)(unsigned short)s) << 16);
}

// BR rows/block, 256 threads (4 waves). Edge: BR=128, 2x2 waves (64x64 tiles).
// Node: BR=32, 1x4 waves (32x32 tiles). W1/W2 fragments loaded direct from
// global (L2-hot). A staging double-buffered. H packed to bf16 in registers,
// spilled to a 32-col LDS chunk per phase-2 round. Phase-2 computes OUT^T via
// mfma(W2frag, Hfrag) so the epilogue is float4-contiguous per lane.
template<int BR, bool IS_EDGE>
__launch_bounds__(256, (BR == 128) ? 3 : 4)
__global__ void mlp_kernel(MlpParams pmA, MlpParams pmB, int blocksA) {
  constexpr int WC    = (BR == 128) ? 2 : 4;   // waves along cols
  constexpr int WR    = 4 / WC;                // waves along rows
  constexpr int WROWS = BR / WR;
  constexpr int WCOLS = 128 / WC;
  constexpr int MREP  = WROWS / 16;
  constexpr int NREP  = WCOLS / 16;
  constexpr int TPR   = 256 / BR;              // staging threads per row
  constexpr int FPT   = 32 / TPR;              // floats per thread per chunk
  constexpr int NV4   = FPT / 4;

  const bool isA = (int)blockIdx.x < blocksA;
  const MlpParams P = isA ? pmA : pmB;
  const int bid  = isA ? (int)blockIdx.x : (int)blockIdx.x - blocksA;
  const int row0 = bid * BR;

  __shared__ __align__(16) short Abuf[2][BR][40];  // stride 80B: 16B-aligned, 2-way banks
  __shared__ __align__(16) short Hbuf[BR][40];     // one 32-k chunk of H
  __shared__ float b1s[128], b2s[128], gs[128], bes[128];
  __shared__ int   idxa[BR], idxb[BR];
  __shared__ float inv1s[BR], inv2s[BR];
  __shared__ float sumL[WC][BR], sqL[WC][BR], muL[BR], rsL[BR];

  const int t = threadIdx.x;

  if (t < 128) { b1s[t] = P.b1[t]; gs[t] = P.gam[t]; }
  else         { b2s[t - 128] = P.b2[t - 128]; bes[t - 128] = P.bet[t - 128]; }
  if (t < BR) {
    if (IS_EDGE) {
      int r = row0 + t;
      idxa[t] = (r < P.nRows) ? P.src[r] : 0;
      idxb[t] = (r < P.nRows) ? P.dst[r] : 0;
    } else {
      int r = min(row0 + t, P.nRows - 1);
      inv1s[t] = P.inv1[r];
      inv2s[t] = P.inv2[r];
    }
  }
  __syncthreads();

  const int l   = t & 63;
  const int wid = t >> 6;
  const int wr  = wid / WC, wcc = wid % WC;
  const int lr  = l & 15,  lg  = l >> 4;

  const int  srow  = t / TPR, sh = t % TPR;
  const int  sgRow = row0 + srow;
  const bool sval  = sgRow < P.nRows;

  int gA = 0, gB = 0; float sc1 = 1.f, sc2 = 1.f;
  if (IS_EDGE) { gA = idxa[srow]; gB = idxb[srow]; }
  else         { sc1 = inv1s[srow]; sc2 = inv2s[srow]; }

  auto loadChunk = [&](int kc, float* v) {
    const int seg = kc >> 2, part = kc & 3;
    if (sval) {
      const float* sbase; float sc = 1.f;
      if (IS_EDGE) {
        sbase = (seg == 0) ? P.x + (size_t)gA * LDIM
              : (seg == 1) ? P.x + (size_t)gB * LDIM
                           : P.attrIn + (size_t)sgRow * LDIM;
      } else {
        if (seg == 0)      { sbase = P.x    + (size_t)sgRow * LDIM; }
        else if (seg == 1) { sbase = P.sum1 + (size_t)sgRow * LDIM; sc = sc1; }
        else               { sbase = P.sum2 + (size_t)sgRow * LDIM; sc = sc2; }
      }
      const float4* s4 = (const float4*)(sbase + part * 32 + sh * FPT);
#pragma unroll
      for (int c = 0; c < NV4; ++c) {
        float4 a = s4[c];
        v[c * 4 + 0] = a.x; v[c * 4 + 1] = a.y; v[c * 4 + 2] = a.z; v[c * 4 + 3] = a.w;
      }
      if (!IS_EDGE && seg != 0) {
#pragma unroll
        for (int e = 0; e < FPT; ++e) v[e] *= sc;
        float4 z = {0.f, 0.f, 0.f, 0.f};
        float4* zp = (float4*)(sbase + part * 32 + sh * FPT);
#pragma unroll
        for (int c = 0; c < NV4; ++c) zp[c] = z;   // zero-after-read (per-step reset)
      }
    } else {
#pragma unroll
      for (int e = 0; e < FPT; ++e) v[e] = 0.f;
    }
  };

  auto storeChunk = [&](int buf, const float* v) {
    if constexpr (FPT == 16) {
      bf16x8 o0, o1;
#pragma unroll
      for (int e = 0; e < 8; ++e) { o0[e] = f2b(v[e]); o1[e] = f2b(v[8 + e]); }
      *(bf16x8*)&Abuf[buf][srow][sh * 16]     = o0;
      *(bf16x8*)&Abuf[buf][srow][sh * 16 + 8] = o1;
    } else {
      bf16x4 o;
#pragma unroll
      for (int e = 0; e < 4; ++e) o[e] = f2b(v[e]);
      *(bf16x4*)&Abuf[buf][srow][sh * 4] = o;
    }
  };

  f32x4 acc[MREP][NREP];
#pragma unroll
  for (int i = 0; i < MREP; ++i)
#pragma unroll
    for (int j = 0; j < NREP; ++j) acc[i][j] = f32x4{0.f, 0.f, 0.f, 0.f};

  // ---------------- phase 1: H = relu(A @ W1 + b1), K = 384 ----------------
  {
    float v0[FPT];
    loadChunk(0, v0);
    storeChunk(0, v0);
  }
  __syncthreads();

  const short* w1hB = P.W1H + (size_t)(wcc * WCOLS + lr) * 384 + lg * 8;
  const short* w1lB = P.W1L + (size_t)(wcc * WCOLS + lr) * 384 + lg * 8;

#pragma unroll
  for (int kc = 0; kc < 12; ++kc) {
    float vnext[FPT];
    if (kc < 11) loadChunk(kc + 1, vnext);       // issue early (hide latency)
    bf16x8 bh[NREP], bl[NREP];
#pragma unroll
    for (int ni = 0; ni < NREP; ++ni) {
      bh[ni] = *(const bf16x8*)(w1hB + (size_t)ni * (16 * 384) + kc * 32);
      bl[ni] = *(const bf16x8*)(w1lB + (size_t)ni * (16 * 384) + kc * 32);
    }
    bf16x8 av[MREP];
#pragma unroll
    for (int mi = 0; mi < MREP; ++mi)
      av[mi] = *(const bf16x8*)&Abuf[kc & 1][wr * WROWS + mi * 16 + lr][lg * 8];
#pragma unroll
    for (int mi = 0; mi < MREP; ++mi)
#pragma unroll
      for (int ni = 0; ni < NREP; ++ni) {
        acc[mi][ni] = __builtin_amdgcn_mfma_f32_16x16x32_bf16(av[mi], bl[ni], acc[mi][ni], 0, 0, 0);
        acc[mi][ni] = __builtin_amdgcn_mfma_f32_16x16x32_bf16(av[mi], bh[ni], acc[mi][ni], 0, 0, 0);
      }
    if (kc < 11) storeChunk((kc + 1) & 1, vnext);  // write late, other buffer
    __syncthreads();
  }

  // pack H = f2b(relu(acc + b1)) into registers; acc dies here
  unsigned int hpk[MREP][NREP][2];
#pragma unroll
  for (int ni = 0; ni < NREP; ++ni) {
    const float bb = b1s[wcc * WCOLS + ni * 16 + lr];
#pragma unroll
    for (int mi = 0; mi < MREP; ++mi)
#pragma unroll
      for (int qp = 0; qp < 2; ++qp) {
        unsigned int lo = (unsigned short)f2b(fmaxf(acc[mi][ni][2 * qp]     + bb, 0.f));
        unsigned int hi = (unsigned short)f2b(fmaxf(acc[mi][ni][2 * qp + 1] + bb, 0.f));
        hpk[mi][ni][qp] = lo | (hi << 16);
      }
  }

  // ---------------- phase 2: OUT^T = W2pre @ H^T, K = 128 (chunked) ----------------
  f32x4 acc2[NREP][MREP];
#pragma unroll
  for (int i = 0; i < NREP; ++i)
#pragma unroll
    for (int j = 0; j < MREP; ++j) acc2[i][j] = f32x4{0.f, 0.f, 0.f, 0.f};

  const short* w2hB = P.W2H + (size_t)(wcc * WCOLS + lr) * 128 + lg * 8;
  const short* w2lB = P.W2L + (size_t)(wcc * WCOLS + lr) * 128 + lg * 8;

#pragma unroll
  for (int kc = 0; kc < 4; ++kc) {
    const int owner = (kc * 32) / WCOLS;
    const int nib   = ((kc * 32) % WCOLS) / 16;
    __syncthreads();                 // previous chunk's readers done
    if (wcc == owner) {
#pragma unroll
      for (int mi = 0; mi < MREP; ++mi)
#pragma unroll
        for (int nio = 0; nio < 2; ++nio) {
          const int ni = nib + nio;
          const int cl = nio * 16 + lr;
#pragma unroll
          for (int qp = 0; qp < 2; ++qp) {
            const int r = wr * WROWS + mi * 16 + lg * 4 + 2 * qp;
            const unsigned int pk = hpk[mi][ni][qp];
            Hbuf[r][cl]     = (short)(pk & 0xffffu);
            Hbuf[r + 1][cl] = (short)(pk >> 16);
          }
        }
    }
    __syncthreads();
    bf16x8 hv[MREP];
#pragma unroll
    for (int mi = 0; mi < MREP; ++mi)
      hv[mi] = *(const bf16x8*)&Hbuf[wr * WROWS + mi * 16 + lr][lg * 8];
    bf16x8 wh[NREP], wl[NREP];
#pragma unroll
    for (int ct = 0; ct < NREP; ++ct) {
      wh[ct] = *(const bf16x8*)(w2hB + (size_t)ct * (16 * 128) + kc * 32);
      wl[ct] = *(const bf16x8*)(w2lB + (size_t)ct * (16 * 128) + kc * 32);
    }
#pragma unroll
    for (int ct = 0; ct < NREP; ++ct)
#pragma unroll
      for (int mi = 0; mi < MREP; ++mi) {
        acc2[ct][mi] = __builtin_amdgcn_mfma_f32_16x16x32_bf16(wl[ct], hv[mi], acc2[ct][mi], 0, 0, 0);
        acc2[ct][mi] = __builtin_amdgcn_mfma_f32_16x16x32_bf16(wh[ct], hv[mi], acc2[ct][mi], 0, 0, 0);
      }
  }

  // ---------------- f32 epilogue: b2 + LN stats ----------------
  // lane holds OUT[r = wr*WROWS + mi*16 + lr][n = wcc*WCOLS + ct*16 + lg*4 + q]
  float s1[MREP], s2[MREP];
#pragma unroll
  for (int mi = 0; mi < MREP; ++mi) { s1[mi] = 0.f; s2[mi] = 0.f; }
#pragma unroll
  for (int ct = 0; ct < NREP; ++ct) {
    const int n0 = wcc * WCOLS + ct * 16 + lg * 4;
#pragma unroll
    for (int q = 0; q < 4; ++q) {
      const float bb = b2s[n0 + q];
#pragma unroll
      for (int mi = 0; mi < MREP; ++mi) {
        const float v = acc2[ct][mi][q] + bb;
        acc2[ct][mi][q] = v;
        s1[mi] += v; s2[mi] += v * v;
      }
    }
  }
#pragma unroll
  for (int mi = 0; mi < MREP; ++mi) {
    s1[mi] += __shfl_xor(s1[mi], 16); s1[mi] += __shfl_xor(s1[mi], 32);
    s2[mi] += __shfl_xor(s2[mi], 16); s2[mi] += __shfl_xor(s2[mi], 32);
  }
  if (lg == 0) {
#pragma unroll
    for (int mi = 0; mi < MREP; ++mi) {
      sumL[wcc][wr * WROWS + mi * 16 + lr] = s1[mi];
      sqL[wcc][wr * WROWS + mi * 16 + lr]  = s2[mi];
    }
  }
  __syncthreads();
  if (t < BR) {
    float tot = 0.f, tsq = 0.f;
#pragma unroll
    for (int w = 0; w < WC; ++w) { tot += sumL[w][t]; tsq += sqL[w][t]; }
    const float mu  = tot * (1.0f / 128.0f);
    const float var = tsq * (1.0f / 128.0f) - mu * mu;
    muL[t] = mu;
    rsL[t] = rsqrtf(var + 1e-5f);
  }
  __syncthreads();

  // hoist per-lane gamma/beta
  float garr[NREP][4], bearr[NREP][4];
#pragma unroll
  for (int ct = 0; ct < NREP; ++ct) {
    const int n0 = wcc * WCOLS + ct * 16 + lg * 4;
#pragma unroll
    for (int q = 0; q < 4; ++q) { garr[ct][q] = gs[n0 + q]; bearr[ct][q] = bes[n0 + q]; }
  }

  // ---------------- normalize + residual + store + (edge) scatter-add ----------------
#pragma unroll
  for (int mi = 0; mi < MREP; ++mi) {
    const int rl   = wr * WROWS + mi * 16 + lr;
    const int grow = row0 + rl;
    if (grow < P.nRows) {
      const float mu = muL[rl], rs = rsL[rl];
      const float* rin  = P.attrIn  + (size_t)grow * LDIM;
      float*       rout = P.attrOut + (size_t)grow * LDIM;
      float* ssum = nullptr;
      if (IS_EDGE) ssum = P.sum1 + (size_t)idxb[rl] * LDIM;
#pragma unroll
      for (int ct = 0; ct < NREP; ++ct) {
        const int n0 = wcc * WCOLS + ct * 16 + lg * 4;
        const float4 old = *(const float4*)(rin + n0);
        float4 oo;
        oo.x = garr[ct][0] * (acc2[ct][mi][0] - mu) * rs + bearr[ct][0] + old.x;
        oo.y = garr[ct][1] * (acc2[ct][mi][1] - mu) * rs + bearr[ct][1] + old.y;
        oo.z = garr[ct][2] * (acc2[ct][mi][2] - mu) * rs + bearr[ct][2] + old.z;
        oo.w = garr[ct][3] * (acc2[ct][mi][3] - mu) * rs + bearr[ct][3] + old.w;
        *(float4*)(rout + n0) = oo;
        if (IS_EDGE) {
          atomicAdd(ssum + n0 + 0, oo.x);
          atomicAdd(ssum + n0 + 1, oo.y);
          atomicAdd(ssum + n0 + 2, oo.z);
          atomicAdd(ssum + n0 + 3, oo.w);
        }
      }
    }
  }
}

// ---- prep kernels ----
__global__ void prep_weights(const float* w1a, const float* w1b, const float* w1c,
                             const float* w2a, const float* w2b, const float* w2c,
                             short* w1h, short* w1l, short* w2h, short* w2l) {
  int i = blockIdx.x * 256 + threadIdx.x;
  constexpr int N1 = 18 * 128 * 384;
  constexpr int N2 = 18 * 128 * 128;
  if (i < N1) {
    int g = i / (128 * 384);
    int rem = i - g * (128 * 384);
    int n = rem / 384, k = rem - n * 384;
    int m = g / 6, s = g - m * 6;
    const float* src = (m == 0) ? w1a : (m == 1) ? w1b : w1c;
    float f = src[(size_t)s * (384 * 128) + (size_t)k * 128 + n];
    short hi = f2b(f);
    w1h[i] = hi;
    w1l[i] = f2b(f - b2f(hi));
  } else if (i < N1 + N2) {
    int j = i - N1;
    int g = j / (128 * 128);
    int rem = j - g * (128 * 128);
    int n = rem / 128, k = rem - n * 128;
    int m = g / 6, s = g - m * 6;
    const float* src = (m == 0) ? w2a : (m == 1) ? w2b : w2c;
    float f = src[(size_t)s * (128 * 128) + (size_t)k * 128 + n];
    short hi = f2b(f);
    w2h[j] = hi;
    w2l[j] = f2b(f - b2f(hi));
  }
}

__global__ void prep_deg(const int* mr, const int* wrcv, int* degm, int* degw) {
  int i = blockIdx.x * 256 + threadIdx.x;
  if (i < EM_N) atomicAdd(&degm[mr[i]], 1);
  else if (i < EM_N + EW_N) atomicAdd(&degw[wrcv[i - EM_N]], 1);
}

__global__ void prep_inv(const int* degm, const int* degw, float* invm, float* invw) {
  int i = blockIdx.x * 256 + threadIdx.x;
  if (i < NNODE) {
    invm[i] = 1.0f / fmaxf((float)degm[i], 1.0f);
    invw[i] = 1.0f / fmaxf((float)degw[i], 1.0f);
  }
}

extern "C" void kernel_launch(void* const* d_in, const int* in_sizes, int n_in,
                              void* d_out, int out_size, void* d_ws, size_t ws_size,
                              hipStream_t stream) {
  (void)in_sizes; (void)n_in; (void)out_size; (void)ws_size;
  const float* x_in   = (const float*)d_in[0];
  const float* mea_in = (const float*)d_in[1];
  const float* wea_in = (const float*)d_in[2];
  const int*   mei    = (const int*)d_in[3];
  const int*   wei    = (const int*)d_in[4];
  const float* W1s[3] = { (const float*)d_in[5],  (const float*)d_in[11], (const float*)d_in[17] };
  const float* B1s[3] = { (const float*)d_in[6],  (const float*)d_in[12], (const float*)d_in[18] };
  const float* W2s[3] = { (const float*)d_in[7],  (const float*)d_in[13], (const float*)d_in[19] };
  const float* B2s[3] = { (const float*)d_in[8],  (const float*)d_in[14], (const float*)d_in[20] };
  const float* Gs[3]  = { (const float*)d_in[9],  (const float*)d_in[15], (const float*)d_in[21] };
  const float* Be[3]  = { (const float*)d_in[10], (const float*)d_in[16], (const float*)d_in[22] };

  float* xo  = (float*)d_out;
  float* meo = xo  + (size_t)NNODE * LDIM;
  float* weo = meo + (size_t)EM_N * LDIM;

  float* msum = (float*)d_ws;
  float* wsum = msum + (size_t)NNODE * LDIM;
  int*   degm = (int*)(wsum + (size_t)NNODE * LDIM);
  int*   degw = degm + NNODE;
  float* invm = (float*)(degw + NNODE);
  float* invw = invm + NNODE;
  short* w1h  = (short*)(invw + NNODE);
  short* w1l  = w1h + (size_t)18 * 128 * 384;
  short* w2h  = w1l + (size_t)18 * 128 * 384;
  short* w2l  = w2h + (size_t)18 * 128 * 128;

  size_t zbytes = (size_t)2 * NNODE * LDIM * 4 + (size_t)2 * NNODE * 4;
  hipMemsetAsync(d_ws, 0, zbytes, stream);

  {
    int tot = 18 * 128 * 384 + 18 * 128 * 128;
    prep_weights<<<dim3((tot + 255) / 256), 256, 0, stream>>>(
        W1s[0], W1s[1], W1s[2], W2s[0], W2s[1], W2s[2], w1h, w1l, w2h, w2l);
  }
  prep_deg<<<dim3((EM_N + EW_N + 255) / 256), 256, 0, stream>>>(mei + EM_N, wei + EW_N, degm, degw);
  prep_inv<<<dim3((NNODE + 255) / 256), 256, 0, stream>>>(degm, degw, invm, invw);

  const int MB = (EM_N + 127) / 128;   // 782
  const int WB = (EW_N + 127) / 128;   // 196
  const int NB = NNODE / 32;           // 625 (exact)

  const float* xc = x_in;
  const float* mc = mea_in;
  const float* wc = wea_in;

  for (int s = 0; s < NSTEP; ++s) {
    MlpParams pm{}, pw{}, pn{};

    pm.x = xc; pm.attrIn = mc; pm.attrOut = meo;
    pm.src = mei; pm.dst = mei + EM_N;
    pm.sum1 = msum;
    pm.W1H = w1h + (size_t)(0 * 6 + s) * 128 * 384;
    pm.W1L = w1l + (size_t)(0 * 6 + s) * 128 * 384;
    pm.W2H = w2h + (size_t)(0 * 6 + s) * 128 * 128;
    pm.W2L = w2l + (size_t)(0 * 6 + s) * 128 * 128;
    pm.b1 = B1s[0] + s * LDIM; pm.b2 = B2s[0] + s * LDIM;
    pm.gam = Gs[0] + s * LDIM; pm.bet = Be[0] + s * LDIM;
    pm.nRows = EM_N;

    pw.x = xc; pw.attrIn = wc; pw.attrOut = weo;
    pw.src = wei; pw.dst = wei + EW_N;
    pw.sum1 = wsum;
    pw.W1H = w1h + (size_t)(1 * 6 + s) * 128 * 384;
    pw.W1L = w1l + (size_t)(1 * 6 + s) * 128 * 384;
    pw.W2H = w2h + (size_t)(1 * 6 + s) * 128 * 128;
    pw.W2L = w2l + (size_t)(1 * 6 + s) * 128 * 128;
    pw.b1 = B1s[1] + s * LDIM; pw.b2 = B2s[1] + s * LDIM;
    pw.gam = Gs[1] + s * LDIM; pw.bet = Be[1] + s * LDIM;
    pw.nRows = EW_N;

    mlp_kernel<128, true><<<dim3(MB + WB), 256, 0, stream>>>(pm, pw, MB);

    pn.x = xc; pn.attrIn = xc; pn.attrOut = xo;
    pn.sum1 = msum; pn.sum2 = wsum; pn.inv1 = invm; pn.inv2 = invw;
    pn.W1H = w1h + (size_t)(2 * 6 + s) * 128 * 384;
    pn.W1L = w1l + (size_t)(2 * 6 + s) * 128 * 384;
    pn.W2H = w2h + (size_t)(2 * 6 + s) * 128 * 128;
    pn.W2L = w2l + (size_t)(2 * 6 + s) * 128 * 128;
    pn.b1 = B1s[2] + s * LDIM; pn.b2 = B2s[2] + s * LDIM;
    pn.gam = Gs[2] + s * LDIM; pn.bet = Be[2] + s * LDIM;
    pn.nRows = NNODE;

    mlp_kernel<32, false><<<dim3(NB), 256, 0, stream>>>(pn, pn, NB);

    xc = xo; mc = meo; wc = weo;
  }
}

// Round 5
// 1690.328 us; speedup vs baseline: 1.1199x; 1.1199x over previous
//
#include <hip/hip_runtime.h>

constexpr int LDIM  = 128;
constexpr int NNODE = 20000;
constexpr int EM_N  = 100000;
constexpr int EW_N  = 25000;
constexpr int NSTEP = 6;

typedef short bf16x8 __attribute__((ext_vector_type(8)));
typedef short bf16x4 __attribute__((ext_vector_type(4)));
typedef float f32x4  __attribute__((ext_vector_type(4)));

struct MlpParams {
  const float* x;
  const float* attrIn;
  float*       attrOut;
  const int*   src;
  const int*   dst;
  float*       sum1;    // edge: scatter target; node: mesh sum (zeroed after read)
  float*       sum2;    // node: world sum (zeroed after read)
  const float* inv1;
  const float* inv2;
  const short* W1H;     // bf16 [128 n][384 k]
  const short* W2H;     // bf16 hi [128 n][128 k]
  const short* W2L;     // bf16 lo
  const float* b1;
  const float* b2;
  const float* gam;
  const float* bet;
  int nRows;
};

__device__ __forceinline__ short f2b(float f) {
  unsigned int u = __float_as_uint(f);
  u = (u + 0x7fffu + ((u >> 16) & 1u)) >> 16;
  return (short)u;
}
__device__ __forceinline__ float b2f(short s) {
  return __uint_as_float(((unsigned int)(unsigned short)s) << 16);
}
__device__ __forceinline__ bf16x4 cvt4(float4 a, float sc) {
  bf16x4 o;
  o[0] = f2b(a.x * sc); o[1] = f2b(a.y * sc);
  o[2] = f2b(a.z * sc); o[3] = f2b(a.w * sc);
  return o;
}

// BR rows/block, 256 threads (4 waves). Edge: BR=128 (2x2 waves, 64x64 tile).
// Node: BR=32 (1x4 waves, 32x32 tile). W1 staged bf16 in LDS per 32-k chunk;
// A gathered+converted via named-register prefetch (issue after barrier, store
// next iter — NO arrays through lambdas: R4's scratch-spill lesson). Phase 2:
// OUT^T = mfma(W2frag, Hfrag), W2 hi/lo direct from L2, H chunk-spilled to LDS
// from register-packed hpk. LN epilogue in f32 from accumulators.
template<int BR, bool IS_EDGE>
__launch_bounds__(256, 3)
__global__ void mlp_kernel(MlpParams pmA, MlpParams pmB, int blocksA) {
  constexpr int WC    = (BR == 128) ? 2 : 4;
  constexpr int WR    = 4 / WC;
  constexpr int WROWS = BR / WR;     // 64 / 32
  constexpr int WCOLS = 128 / WC;    // 64 / 32
  constexpr int MREP  = WROWS / 16;  // 4 / 2
  constexpr int NREP  = WCOLS / 16;  // 4 / 2
  constexpr int TPR   = 256 / BR;    // 2 / 8
  constexpr int FPT   = 32 / TPR;    // 16 / 4

  const bool isA = (int)blockIdx.x < blocksA;
  const MlpParams P = isA ? pmA : pmB;
  const int bid  = isA ? (int)blockIdx.x : (int)blockIdx.x - blocksA;
  const int row0 = bid * BR;

  __shared__ __align__(16) short Abuf[BR][40];   // stride 80B: aligned, 2-way banks
  __shared__ __align__(16) short Bbuf[128][40];  // W1 chunk
  __shared__ __align__(16) short Hch[BR][40];    // one 32-k chunk of H
  __shared__ float b1s[128], b2s[128], gs[128], bes[128];
  __shared__ int   idxa[BR], idxb[BR];
  __shared__ float inv1s[BR], inv2s[BR];
  __shared__ float sumL[WC][BR], sqL[WC][BR], muL[BR], rsL[BR];

  const int t = threadIdx.x;

  if (t < 128) { b1s[t] = P.b1[t]; gs[t] = P.gam[t]; }
  else         { b2s[t - 128] = P.b2[t - 128]; bes[t - 128] = P.bet[t - 128]; }
  if (t < BR) {
    if (IS_EDGE) {
      int r = row0 + t;
      idxa[t] = (r < P.nRows) ? P.src[r] : 0;
      idxb[t] = (r < P.nRows) ? P.dst[r] : 0;
    } else {
      int r = min(row0 + t, P.nRows - 1);
      inv1s[t] = P.inv1[r];
      inv2s[t] = P.inv2[r];
    }
  }
  __syncthreads();

  const int l   = t & 63;
  const int wid = t >> 6;
  const int wr  = wid / WC, wcc = wid % WC;
  const int lr  = l & 15,  lg  = l >> 4;

  const int  srow  = t / TPR, sh = t % TPR;
  const int  sgRow = row0 + srow;
  const bool sval  = sgRow < P.nRows;
  const int  sgC   = sval ? sgRow : 0;
  const float vmask = sval ? 1.f : 0.f;

  // per-thread A base pointers for the 3 input segments (incl. sh offset)
  const float* base0; const float* base1; const float* base2;
  float sc1v = vmask, sc2v = vmask;
  if (IS_EDGE) {
    base0 = P.x + (size_t)idxa[srow] * LDIM + sh * FPT;
    base1 = P.x + (size_t)idxb[srow] * LDIM + sh * FPT;
    base2 = P.attrIn + (size_t)sgC * LDIM + sh * FPT;
  } else {
    base0 = P.x    + (size_t)sgC * LDIM + sh * FPT;
    base1 = P.sum1 + (size_t)sgC * LDIM + sh * FPT;
    base2 = P.sum2 + (size_t)sgC * LDIM + sh * FPT;
    sc1v = inv1s[srow] * vmask;
    sc2v = inv2s[srow] * vmask;
  }

  // W1 staging: 2 threads/row over all 128 n-rows
  const int wrow = t >> 1, wsh = t & 1;
  const short* wbase = P.W1H + (size_t)wrow * 384 + wsh * 16;

  f32x4 acc[MREP][NREP];
#pragma unroll
  for (int i = 0; i < MREP; ++i)
#pragma unroll
    for (int j = 0; j < NREP; ++j) acc[i][j] = f32x4{0.f, 0.f, 0.f, 0.f};

  // named prefetch registers (no arrays -> no scratch)
  float4 pA0, pA1, pA2, pA3;
  bf16x8 pW0, pW1;

  // preload chunk 0
  {
    const float4* bp = (const float4*)base0;
    pA0 = bp[0];
    if constexpr (FPT == 16) { pA1 = bp[1]; pA2 = bp[2]; pA3 = bp[3]; }
    pW0 = *(const bf16x8*)(wbase);
    pW1 = *(const bf16x8*)(wbase + 8);
  }

  // ---------------- phase 1: H = relu(A @ W1 + b1), K = 384 ----------------
#pragma unroll
  for (int kc = 0; kc < 12; ++kc) {
    const int seg = kc >> 2, part = kc & 3;
    if (kc > 0) __syncthreads();          // staging buffers free
    {
      const float scK = (seg == 0) ? vmask : (seg == 1) ? sc1v : sc2v;
      if constexpr (FPT == 16) {
        *(bf16x4*)&Abuf[srow][sh * 16 + 0]  = cvt4(pA0, scK);
        *(bf16x4*)&Abuf[srow][sh * 16 + 4]  = cvt4(pA1, scK);
        *(bf16x4*)&Abuf[srow][sh * 16 + 8]  = cvt4(pA2, scK);
        *(bf16x4*)&Abuf[srow][sh * 16 + 12] = cvt4(pA3, scK);
      } else {
        *(bf16x4*)&Abuf[srow][sh * 4] = cvt4(pA0, scK);
      }
      *(bf16x8*)&Bbuf[wrow][wsh * 16]     = pW0;
      *(bf16x8*)&Bbuf[wrow][wsh * 16 + 8] = pW1;
      if constexpr (!IS_EDGE) {
        if (seg != 0 && sval) {           // zero-after-read (value consumed above)
          float4 z = {0.f, 0.f, 0.f, 0.f};
          float4* zp = (float4*)((seg == 1 ? base1 : base2) + part * 32);
          zp[0] = z;
          if constexpr (FPT == 16) { zp[1] = z; zp[2] = z; zp[3] = z; }
        }
      }
    }
    __syncthreads();                      // data ready
    if (kc < 11) {                        // issue next-chunk loads (fly over MFMA)
      const int kn = kc + 1, segn = kn >> 2, partn = kn & 3;
      const float4* bp = (const float4*)((segn == 0 ? base0 : segn == 1 ? base1 : base2) + partn * 32);
      pA0 = bp[0];
      if constexpr (FPT == 16) { pA1 = bp[1]; pA2 = bp[2]; pA3 = bp[3]; }
      pW0 = *(const bf16x8*)(wbase + kn * 32);
      pW1 = *(const bf16x8*)(wbase + kn * 32 + 8);
    }
    bf16x8 av[MREP], bh[NREP];
#pragma unroll
    for (int mi = 0; mi < MREP; ++mi)
      av[mi] = *(const bf16x8*)&Abuf[wr * WROWS + mi * 16 + lr][lg * 8];
#pragma unroll
    for (int ni = 0; ni < NREP; ++ni)
      bh[ni] = *(const bf16x8*)&Bbuf[wcc * WCOLS + ni * 16 + lr][lg * 8];
#pragma unroll
    for (int mi = 0; mi < MREP; ++mi)
#pragma unroll
      for (int ni = 0; ni < NREP; ++ni)
        acc[mi][ni] = __builtin_amdgcn_mfma_f32_16x16x32_bf16(av[mi], bh[ni], acc[mi][ni], 0, 0, 0);
  }

  // pack H = f2b(relu(acc + b1)) into registers; acc dies here
  unsigned int hpk[MREP][NREP][2];
#pragma unroll
  for (int ni = 0; ni < NREP; ++ni) {
    const float bb = b1s[wcc * WCOLS + ni * 16 + lr];
#pragma unroll
    for (int mi = 0; mi < MREP; ++mi)
#pragma unroll
      for (int qp = 0; qp < 2; ++qp) {
        unsigned int lo = (unsigned short)f2b(fmaxf(acc[mi][ni][2 * qp]     + bb, 0.f));
        unsigned int hi = (unsigned short)f2b(fmaxf(acc[mi][ni][2 * qp + 1] + bb, 0.f));
        hpk[mi][ni][qp] = lo | (hi << 16);
      }
  }

  // ---------------- phase 2: OUT^T = W2 @ H^T, K = 128 (chunked) ----------------
  f32x4 acc2[NREP][MREP];
#pragma unroll
  for (int i = 0; i < NREP; ++i)
#pragma unroll
    for (int j = 0; j < MREP; ++j) acc2[i][j] = f32x4{0.f, 0.f, 0.f, 0.f};

  const short* w2hB = P.W2H + (size_t)(wcc * WCOLS + lr) * 128 + lg * 8;
  const short* w2lB = P.W2L + (size_t)(wcc * WCOLS + lr) * 128 + lg * 8;

#pragma unroll
  for (int kc = 0; kc < 4; ++kc) {
    const int owner = (kc * 32) / WCOLS;
    const int nib   = ((kc * 32) % WCOLS) / 16;
    __syncthreads();                      // previous chunk's readers done
    if (wcc == owner) {
#pragma unroll
      for (int mi = 0; mi < MREP; ++mi)
#pragma unroll
        for (int nio = 0; nio < 2; ++nio) {
          const int ni = nib + nio;
          const int cl = nio * 16 + lr;
#pragma unroll
          for (int qp = 0; qp < 2; ++qp) {
            const int r = wr * WROWS + mi * 16 + lg * 4 + 2 * qp;
            const unsigned int pk = hpk[mi][ni][qp];
            Hch[r][cl]     = (short)(pk & 0xffffu);
            Hch[r + 1][cl] = (short)(pk >> 16);
          }
        }
    }
    __syncthreads();
    bf16x8 hv[MREP], wh[NREP], wl[NREP];
#pragma unroll
    for (int mi = 0; mi < MREP; ++mi)
      hv[mi] = *(const bf16x8*)&Hch[wr * WROWS + mi * 16 + lr][lg * 8];
#pragma unroll
    for (int ct = 0; ct < NREP; ++ct) {
      wh[ct] = *(const bf16x8*)(w2hB + (size_t)ct * (16 * 128) + kc * 32);
      wl[ct] = *(const bf16x8*)(w2lB + (size_t)ct * (16 * 128) + kc * 32);
    }
#pragma unroll
    for (int ct = 0; ct < NREP; ++ct)
#pragma unroll
      for (int mi = 0; mi < MREP; ++mi) {
        acc2[ct][mi] = __builtin_amdgcn_mfma_f32_16x16x32_bf16(wl[ct], hv[mi], acc2[ct][mi], 0, 0, 0);
        acc2[ct][mi] = __builtin_amdgcn_mfma_f32_16x16x32_bf16(wh[ct], hv[mi], acc2[ct][mi], 0, 0, 0);
      }
  }

  // ---------------- f32 epilogue: b2 + LN stats ----------------
  // lane holds OUT[r = wr*WROWS + mi*16 + lr][n = wcc*WCOLS + ct*16 + lg*4 + q]
  float s1[MREP], s2[MREP];
#pragma unroll
  for (int mi = 0; mi < MREP; ++mi) { s1[mi] = 0.f; s2[mi] = 0.f; }
#pragma unroll
  for (int ct = 0; ct < NREP; ++ct) {
    const int n0 = wcc * WCOLS + ct * 16 + lg * 4;
#pragma unroll
    for (int q = 0; q < 4; ++q) {
      const float bb = b2s[n0 + q];
#pragma unroll
      for (int mi = 0; mi < MREP; ++mi) {
        const float v = acc2[ct][mi][q] + bb;
        acc2[ct][mi][q] = v;
        s1[mi] += v; s2[mi] += v * v;
      }
    }
  }
#pragma unroll
  for (int mi = 0; mi < MREP; ++mi) {
    s1[mi] += __shfl_xor(s1[mi], 16); s1[mi] += __shfl_xor(s1[mi], 32);
    s2[mi] += __shfl_xor(s2[mi], 16); s2[mi] += __shfl_xor(s2[mi], 32);
  }
  if (lg == 0) {
#pragma unroll
    for (int mi = 0; mi < MREP; ++mi) {
      sumL[wcc][wr * WROWS + mi * 16 + lr] = s1[mi];
      sqL[wcc][wr * WROWS + mi * 16 + lr]  = s2[mi];
    }
  }
  __syncthreads();
  if (t < BR) {
    float tot = 0.f, tsq = 0.f;
#pragma unroll
    for (int w = 0; w < WC; ++w) { tot += sumL[w][t]; tsq += sqL[w][t]; }
    const float mu  = tot * (1.0f / 128.0f);
    const float var = tsq * (1.0f / 128.0f) - mu * mu;
    muL[t] = mu;
    rsL[t] = rsqrtf(var + 1e-5f);
  }
  __syncthreads();

  float garr[NREP][4], bearr[NREP][4];
#pragma unroll
  for (int ct = 0; ct < NREP; ++ct) {
    const int n0 = wcc * WCOLS + ct * 16 + lg * 4;
#pragma unroll
    for (int q = 0; q < 4; ++q) { garr[ct][q] = gs[n0 + q]; bearr[ct][q] = bes[n0 + q]; }
  }

  // ---------------- normalize + residual + store + (edge) scatter-add ----------------
#pragma unroll
  for (int mi = 0; mi < MREP; ++mi) {
    const int rl   = wr * WROWS + mi * 16 + lr;
    const int grow = row0 + rl;
    if (grow < P.nRows) {
      const float mu = muL[rl], rs = rsL[rl];
      const float* rin  = P.attrIn  + (size_t)grow * LDIM;
      float*       rout = P.attrOut + (size_t)grow * LDIM;
      float* ssum = nullptr;
      if (IS_EDGE) ssum = P.sum1 + (size_t)idxb[rl] * LDIM;
#pragma unroll
      for (int ct = 0; ct < NREP; ++ct) {
        const int n0 = wcc * WCOLS + ct * 16 + lg * 4;
        const float4 old = *(const float4*)(rin + n0);
        float4 oo;
        oo.x = garr[ct][0] * (acc2[ct][mi][0] - mu) * rs + bearr[ct][0] + old.x;
        oo.y = garr[ct][1] * (acc2[ct][mi][1] - mu) * rs + bearr[ct][1] + old.y;
        oo.z = garr[ct][2] * (acc2[ct][mi][2] - mu) * rs + bearr[ct][2] + old.z;
        oo.w = garr[ct][3] * (acc2[ct][mi][3] - mu) * rs + bearr[ct][3] + old.w;
        *(float4*)(rout + n0) = oo;
        if (IS_EDGE) {
          atomicAdd(ssum + n0 + 0, oo.x);
          atomicAdd(ssum + n0 + 1, oo.y);
          atomicAdd(ssum + n0 + 2, oo.z);
          atomicAdd(ssum + n0 + 3, oo.w);
        }
      }
    }
  }
}

// ---- prep kernels ----
__global__ void prep_weights(const float* w1a, const float* w1b, const float* w1c,
                             const float* w2a, const float* w2b, const float* w2c,
                             short* w1h, short* w2h, short* w2l) {
  int i = blockIdx.x * 256 + threadIdx.x;
  constexpr int N1 = 18 * 128 * 384;
  constexpr int N2 = 18 * 128 * 128;
  if (i < N1) {
    int g = i / (128 * 384);
    int rem = i - g * (128 * 384);
    int n = rem / 384, k = rem - n * 384;
    int m = g / 6, s = g - m * 6;
    const float* src = (m == 0) ? w1a : (m == 1) ? w1b : w1c;
    w1h[i] = f2b(src[(size_t)s * (384 * 128) + (size_t)k * 128 + n]);
  } else if (i < N1 + N2) {
    int j = i - N1;
    int g = j / (128 * 128);
    int rem = j - g * (128 * 128);
    int n = rem / 128, k = rem - n * 128;
    int m = g / 6, s = g - m * 6;
    const float* src = (m == 0) ? w2a : (m == 1) ? w2b : w2c;
    float f = src[(size_t)s * (128 * 128) + (size_t)k * 128 + n];
    short hi = f2b(f);
    w2h[j] = hi;
    w2l[j] = f2b(f - b2f(hi));
  }
}

__global__ void prep_deg(const int* mr, const int* wrcv, int* degm, int* degw) {
  int i = blockIdx.x * 256 + threadIdx.x;
  if (i < EM_N) atomicAdd(&degm[mr[i]], 1);
  else if (i < EM_N + EW_N) atomicAdd(&degw[wrcv[i - EM_N]], 1);
}

__global__ void prep_inv(const int* degm, const int* degw, float* invm, float* invw) {
  int i = blockIdx.x * 256 + threadIdx.x;
  if (i < NNODE) {
    invm[i] = 1.0f / fmaxf((float)degm[i], 1.0f);
    invw[i] = 1.0f / fmaxf((float)degw[i], 1.0f);
  }
}

extern "C" void kernel_launch(void* const* d_in, const int* in_sizes, int n_in,
                              void* d_out, int out_size, void* d_ws, size_t ws_size,
                              hipStream_t stream) {
  (void)in_sizes; (void)n_in; (void)out_size; (void)ws_size;
  const float* x_in   = (const float*)d_in[0];
  const float* mea_in = (const float*)d_in[1];
  const float* wea_in = (const float*)d_in[2];
  const int*   mei    = (const int*)d_in[3];
  const int*   wei    = (const int*)d_in[4];
  const float* W1s[3] = { (const float*)d_in[5],  (const float*)d_in[11], (const float*)d_in[17] };
  const float* B1s[3] = { (const float*)d_in[6],  (const float*)d_in[12], (const float*)d_in[18] };
  const float* W2s[3] = { (const float*)d_in[7],  (const float*)d_in[13], (const float*)d_in[19] };
  const float* B2s[3] = { (const float*)d_in[8],  (const float*)d_in[14], (const float*)d_in[20] };
  const float* Gs[3]  = { (const float*)d_in[9],  (const float*)d_in[15], (const float*)d_in[21] };
  const float* Be[3]  = { (const float*)d_in[10], (const float*)d_in[16], (const float*)d_in[22] };

  float* xo  = (float*)d_out;
  float* meo = xo  + (size_t)NNODE * LDIM;
  float* weo = meo + (size_t)EM_N * LDIM;

  float* msum = (float*)d_ws;
  float* wsum = msum + (size_t)NNODE * LDIM;
  int*   degm = (int*)(wsum + (size_t)NNODE * LDIM);
  int*   degw = degm + NNODE;
  float* invm = (float*)(degw + NNODE);
  float* invw = invm + NNODE;
  short* w1h  = (short*)(invw + NNODE);
  short* w2h  = w1h + (size_t)18 * 128 * 384;
  short* w2l  = w2h + (size_t)18 * 128 * 128;

  size_t zbytes = (size_t)2 * NNODE * LDIM * 4 + (size_t)2 * NNODE * 4;
  hipMemsetAsync(d_ws, 0, zbytes, stream);

  {
    int tot = 18 * 128 * 384 + 18 * 128 * 128;
    prep_weights<<<dim3((tot + 255) / 256), 256, 0, stream>>>(
        W1s[0], W1s[1], W1s[2], W2s[0], W2s[1], W2s[2], w1h, w2h, w2l);
  }
  prep_deg<<<dim3((EM_N + EW_N + 255) / 256), 256, 0, stream>>>(mei + EM_N, wei + EW_N, degm, degw);
  prep_inv<<<dim3((NNODE + 255) / 256), 256, 0, stream>>>(degm, degw, invm, invw);

  const int MB = (EM_N + 127) / 128;   // 782
  const int WB = (EW_N + 127) / 128;   // 196
  const int NB = NNODE / 32;           // 625 (exact)

  const float* xc = x_in;
  const float* mc = mea_in;
  const float* wc = wea_in;

  for (int s = 0; s < NSTEP; ++s) {
    MlpParams pm{}, pw{}, pn{};

    pm.x = xc; pm.attrIn = mc; pm.attrOut = meo;
    pm.src = mei; pm.dst = mei + EM_N;
    pm.sum1 = msum;
    pm.W1H = w1h + (size_t)(0 * 6 + s) * 128 * 384;
    pm.W2H = w2h + (size_t)(0 * 6 + s) * 128 * 128;
    pm.W2L = w2l + (size_t)(0 * 6 + s) * 128 * 128;
    pm.b1 = B1s[0] + s * LDIM; pm.b2 = B2s[0] + s * LDIM;
    pm.gam = Gs[0] + s * LDIM; pm.bet = Be[0] + s * LDIM;
    pm.nRows = EM_N;

    pw.x = xc; pw.attrIn = wc; pw.attrOut = weo;
    pw.src = wei; pw.dst = wei + EW_N;
    pw.sum1 = wsum;
    pw.W1H = w1h + (size_t)(1 * 6 + s) * 128 * 384;
    pw.W2H = w2h + (size_t)(1 * 6 + s) * 128 * 128;
    pw.W2L = w2l + (size_t)(1 * 6 + s) * 128 * 128;
    pw.b1 = B1s[1] + s * LDIM; pw.b2 = B2s[1] + s * LDIM;
    pw.gam = Gs[1] + s * LDIM; pw.bet = Be[1] + s * LDIM;
    pw.nRows = EW_N;

    mlp_kernel<128, true><<<dim3(MB + WB), 256, 0, stream>>>(pm, pw, MB);

    pn.x = xc; pn.attrIn = xc; pn.attrOut = xo;
    pn.sum1 = msum; pn.sum2 = wsum; pn.inv1 = invm; pn.inv2 = invw;
    pn.W1H = w1h + (size_t)(2 * 6 + s) * 128 * 384;
    pn.W2H = w2h + (size_t)(2 * 6 + s) * 128 * 128;
    pn.W2L = w2l + (size_t)(2 * 6 + s) * 128 * 128;
    pn.b1 = B1s[2] + s * LDIM; pn.b2 = B2s[2] + s * LDIM;
    pn.gam = Gs[2] + s * LDIM; pn.bet = Be[2] + s * LDIM;
    pn.nRows = NNODE;

    mlp_kernel<32, false><<<dim3(NB), 256, 0, stream>>>(pn, pn, NB);

    xc = xo; mc = meo; wc = weo;
  }
}

// Round 6
// 885.952 us; speedup vs baseline: 2.1366x; 1.9079x over previous
//
#include <hip/hip_runtime.h>

constexpr int LDIM  = 128;
constexpr int NNODE = 20000;
constexpr int EM_N  = 100000;
constexpr int EW_N  = 25000;
constexpr int NSTEP = 6;

typedef short bf16x8 __attribute__((ext_vector_type(8)));
typedef short bf16x4 __attribute__((ext_vector_type(4)));
typedef float f32x4  __attribute__((ext_vector_type(4)));

struct MlpParams {
  const float* x;
  const float* attrIn;
  float*       attrOut;
  const int*   src;
  const int*   dst;
  float*       sum1;    // edge: scatter target; node: mesh sum (zeroed after read)
  float*       sum2;    // node: world sum (zeroed after read)
  const float* inv1;
  const float* inv2;
  const short* W1H;     // bf16 [128 n][384 k]
  const short* W2H;     // bf16 hi [128 n][128 k]
  const short* W2L;     // bf16 lo
  const float* b1;
  const float* b2;
  const float* gam;
  const float* bet;
  int nRows;
};

__device__ __forceinline__ short f2b(float f) {
  unsigned int u = __float_as_uint(f);
  u = (u + 0x7fffu + ((u >> 16) & 1u)) >> 16;
  return (short)u;
}
__device__ __forceinline__ float b2f(short s) {
  return __uint_as_float(((unsigned int)(unsigned short)s) << 16);
}
__device__ __forceinline__ bf16x4 cvt4(float4 a, float sc) {
  bf16x4 o;
  o[0] = f2b(a.x * sc); o[1] = f2b(a.y * sc);
  o[2] = f2b(a.z * sc); o[3] = f2b(a.w * sc);
  return o;
}

// R2 structure restored: 128 rows/block, 256 threads (4 waves 2x2, 64x64 wave
// tile), W1 (hi only) + W2 (hi+lo) staged via LDS, full Hbuf[128][136], R2
// epilogue (f32 LN from accumulators) and R2 atomic pattern. Only additions:
// named-register prefetch of next chunk's A/W loads issued after the
// data-ready barrier (latency hidden under MFMA), W1-lo dropped (validated by
// R5: absmax 0.0625 without it).
template<bool IS_EDGE>
__launch_bounds__(256, 2)
__global__ void mlp_kernel(MlpParams pmA, MlpParams pmB, int blocksA) {
  const bool isA = (int)blockIdx.x < blocksA;
  const MlpParams P = isA ? pmA : pmB;
  const int bid  = isA ? (int)blockIdx.x : (int)blockIdx.x - blocksA;
  const int row0 = bid * 128;

  __shared__ __align__(16) short Abuf[128][40];   // stride 80B: aligned + 2-way banks
  __shared__ __align__(16) short Bhi[128][40];
  __shared__ __align__(16) short Blo[128][40];
  __shared__ __align__(16) short Hbuf[128][136];  // stride 272B: aligned + 2-way banks
  __shared__ float b1s[128], b2s[128], gs[128], bes[128];
  __shared__ int   idxa[128], idxb[128];
  __shared__ float inv1s[128], inv2s[128];
  __shared__ float sumL[2][128], sqL[2][128];
  __shared__ float muL[128], rsL[128];

  const int t = threadIdx.x;

  if (t < 128) {
    b1s[t] = P.b1[t];
    gs[t]  = P.gam[t];
    if (IS_EDGE) {
      int r = row0 + t;
      idxa[t] = (r < P.nRows) ? P.src[r] : 0;
    } else {
      int r = min(row0 + t, P.nRows - 1);
      inv1s[t] = P.inv1[r];
    }
  } else {
    int t2 = t - 128;
    b2s[t2] = P.b2[t2];
    bes[t2] = P.bet[t2];
    if (IS_EDGE) {
      int r = row0 + t2;
      idxb[t2] = (r < P.nRows) ? P.dst[r] : 0;
    } else {
      int r = min(row0 + t2, P.nRows - 1);
      inv2s[t2] = P.inv2[r];
    }
  }
  __syncthreads();   // idx/inv tables ready (needed for prefetch base setup)

  const int l   = t & 63;
  const int wid = t >> 6;
  const int wr  = wid >> 1, wcc = wid & 1;
  const int lr  = l & 15,  lg  = l >> 4;

  const int  srow  = t >> 1, sh = t & 1;   // staging row assignment (2 thr/row)
  const int  sgRow = row0 + srow;
  const bool sval  = sgRow < P.nRows;
  const int  sgC   = sval ? sgRow : 0;
  const float vmask = sval ? 1.f : 0.f;

  // per-thread A base pointers for the 3 input segments (incl. sh offset)
  const float* base0; const float* base1; const float* base2;
  float sc1v = vmask, sc2v = vmask;
  if (IS_EDGE) {
    base0 = P.x + (size_t)idxa[srow] * LDIM + sh * 16;
    base1 = P.x + (size_t)idxb[srow] * LDIM + sh * 16;
    base2 = P.attrIn + (size_t)sgC * LDIM + sh * 16;
  } else {
    base0 = P.x    + (size_t)sgC * LDIM + sh * 16;
    base1 = P.sum1 + (size_t)sgC * LDIM + sh * 16;
    base2 = P.sum2 + (size_t)sgC * LDIM + sh * 16;
    sc1v = inv1s[srow] * vmask;
    sc2v = inv2s[srow] * vmask;
  }

  // weight staging assignment (2 thr/row over 128 n-rows)
  const int wrow = t >> 1, wsh = t & 1;
  const short* w1base = P.W1H + (size_t)wrow * 384 + wsh * 16;

  f32x4 acc[4][4];
#pragma unroll
  for (int i = 0; i < 4; ++i)
#pragma unroll
    for (int j = 0; j < 4; ++j) acc[i][j] = f32x4{0.f, 0.f, 0.f, 0.f};

  // named prefetch registers
  float4 pA0, pA1, pA2, pA3;
  bf16x8 pW0, pW1;
  {
    const float4* bp = (const float4*)base0;
    pA0 = bp[0]; pA1 = bp[1]; pA2 = bp[2]; pA3 = bp[3];
    pW0 = *(const bf16x8*)w1base;
    pW1 = *(const bf16x8*)(w1base + 8);
  }

  // ---------------- phase 1: H = relu(A @ W1 + b1), K = 384 ----------------
#pragma unroll
  for (int kc = 0; kc < 12; ++kc) {
    const int seg = kc >> 2, part = kc & 3;
    if (kc > 0) __syncthreads();          // staging buffers free
    {
      const float scK = (seg == 0) ? vmask : (seg == 1) ? sc1v : sc2v;
      *(bf16x4*)&Abuf[srow][sh * 16 + 0]  = cvt4(pA0, scK);
      *(bf16x4*)&Abuf[srow][sh * 16 + 4]  = cvt4(pA1, scK);
      *(bf16x4*)&Abuf[srow][sh * 16 + 8]  = cvt4(pA2, scK);
      *(bf16x4*)&Abuf[srow][sh * 16 + 12] = cvt4(pA3, scK);
      *(bf16x8*)&Bhi[wrow][wsh * 16]     = pW0;
      *(bf16x8*)&Bhi[wrow][wsh * 16 + 8] = pW1;
      if constexpr (!IS_EDGE) {
        if (seg != 0 && sval) {           // zero-after-read (value already in regs)
          float4 z = {0.f, 0.f, 0.f, 0.f};
          float4* zp = (float4*)((seg == 1 ? base1 : base2) + part * 32);
          zp[0] = z; zp[1] = z; zp[2] = z; zp[3] = z;
        }
      }
    }
    __syncthreads();                      // data ready
    if (kc < 11) {                        // issue next-chunk loads; fly over MFMAs
      const int kn = kc + 1, segn = kn >> 2, partn = kn & 3;
      const float4* bp = (const float4*)((segn == 0 ? base0 : segn == 1 ? base1 : base2) + partn * 32);
      pA0 = bp[0]; pA1 = bp[1]; pA2 = bp[2]; pA3 = bp[3];
      pW0 = *(const bf16x8*)(w1base + kn * 32);
      pW1 = *(const bf16x8*)(w1base + kn * 32 + 8);
    }
    bf16x8 av[4], bh[4];
#pragma unroll
    for (int mi = 0; mi < 4; ++mi)
      av[mi] = *(const bf16x8*)&Abuf[wr * 64 + mi * 16 + lr][lg * 8];
#pragma unroll
    for (int ni = 0; ni < 4; ++ni)
      bh[ni] = *(const bf16x8*)&Bhi[wcc * 64 + ni * 16 + lr][lg * 8];
#pragma unroll
    for (int mi = 0; mi < 4; ++mi)
#pragma unroll
      for (int ni = 0; ni < 4; ++ni)
        acc[mi][ni] = __builtin_amdgcn_mfma_f32_16x16x32_bf16(av[mi], bh[ni], acc[mi][ni], 0, 0, 0);
  }

  // write H = relu(acc + b1) to LDS as bf16 (R2 verbatim)
#pragma unroll
  for (int rt = 0; rt < 4; ++rt)
#pragma unroll
    for (int ct = 0; ct < 4; ++ct) {
      const int cc = wcc * 64 + ct * 16 + lr;
      const float bb = b1s[cc];
#pragma unroll
      for (int q = 0; q < 4; ++q) {
        const int rr = wr * 64 + rt * 16 + lg * 4 + q;
        Hbuf[rr][cc] = f2b(fmaxf(acc[rt][ct][q] + bb, 0.f));
      }
    }

  // ---------------- phase 2: OUT = H @ W2 + b2, K = 128 ----------------
  f32x4 acc2[4][4];
#pragma unroll
  for (int i = 0; i < 4; ++i)
#pragma unroll
    for (int j = 0; j < 4; ++j) acc2[i][j] = f32x4{0.f, 0.f, 0.f, 0.f};

  const short* w2hbase = P.W2H + (size_t)wrow * 128 + wsh * 16;
  const short* w2lbase = P.W2L + (size_t)wrow * 128 + wsh * 16;

  bf16x8 qh0, qh1, ql0, ql1;
  qh0 = *(const bf16x8*)w2hbase;
  qh1 = *(const bf16x8*)(w2hbase + 8);
  ql0 = *(const bf16x8*)w2lbase;
  ql1 = *(const bf16x8*)(w2lbase + 8);

#pragma unroll
  for (int kc = 0; kc < 4; ++kc) {
    __syncthreads();   // kc=0: publishes Hbuf + phase-1 Bhi readers done; else prev readers done
    {
      *(bf16x8*)&Bhi[wrow][wsh * 16]     = qh0;
      *(bf16x8*)&Bhi[wrow][wsh * 16 + 8] = qh1;
      *(bf16x8*)&Blo[wrow][wsh * 16]     = ql0;
      *(bf16x8*)&Blo[wrow][wsh * 16 + 8] = ql1;
    }
    __syncthreads();
    if (kc < 3) {
      qh0 = *(const bf16x8*)(w2hbase + (kc + 1) * 32);
      qh1 = *(const bf16x8*)(w2hbase + (kc + 1) * 32 + 8);
      ql0 = *(const bf16x8*)(w2lbase + (kc + 1) * 32);
      ql1 = *(const bf16x8*)(w2lbase + (kc + 1) * 32 + 8);
    }
    bf16x8 av2[4], bh2[4], bl2[4];
#pragma unroll
    for (int rt = 0; rt < 4; ++rt)
      av2[rt] = *(const bf16x8*)&Hbuf[wr * 64 + rt * 16 + lr][kc * 32 + lg * 8];
#pragma unroll
    for (int ct = 0; ct < 4; ++ct) {
      bh2[ct] = *(const bf16x8*)&Bhi[wcc * 64 + ct * 16 + lr][lg * 8];
      bl2[ct] = *(const bf16x8*)&Blo[wcc * 64 + ct * 16 + lr][lg * 8];
    }
#pragma unroll
    for (int rt = 0; rt < 4; ++rt)
#pragma unroll
      for (int ct = 0; ct < 4; ++ct) {
        acc2[rt][ct] = __builtin_amdgcn_mfma_f32_16x16x32_bf16(av2[rt], bl2[ct], acc2[rt][ct], 0, 0, 0);
        acc2[rt][ct] = __builtin_amdgcn_mfma_f32_16x16x32_bf16(av2[rt], bh2[ct], acc2[rt][ct], 0, 0, 0);
      }
  }

  // ---------------- f32 epilogue: b2 + LN stats from registers (R2 verbatim) ----------------
  float s1[4][4], s2[4][4];
#pragma unroll
  for (int rt = 0; rt < 4; ++rt)
#pragma unroll
    for (int q = 0; q < 4; ++q) { s1[rt][q] = 0.f; s2[rt][q] = 0.f; }
#pragma unroll
  for (int rt = 0; rt < 4; ++rt)
#pragma unroll
    for (int ct = 0; ct < 4; ++ct) {
      const float bb = b2s[wcc * 64 + ct * 16 + lr];
#pragma unroll
      for (int q = 0; q < 4; ++q) {
        float v = acc2[rt][ct][q] + bb;
        acc2[rt][ct][q] = v;
        s1[rt][q] += v;
        s2[rt][q] += v * v;
      }
    }
#pragma unroll
  for (int m = 1; m < 16; m <<= 1) {
#pragma unroll
    for (int rt = 0; rt < 4; ++rt)
#pragma unroll
      for (int q = 0; q < 4; ++q) {
        s1[rt][q] += __shfl_xor(s1[rt][q], m);
        s2[rt][q] += __shfl_xor(s2[rt][q], m);
      }
  }
  __syncthreads();
  {
    const int rt = lr >> 2, q = lr & 3;
    const int rr = wr * 64 + rt * 16 + lg * 4 + q;
    sumL[wcc][rr] = s1[rt][q];
    sqL[wcc][rr]  = s2[rt][q];
  }
  __syncthreads();
  if (t < 128) {
    const float tot = sumL[0][t] + sumL[1][t];
    const float tsq = sqL[0][t] + sqL[1][t];
    const float mu  = tot * (1.0f / 128.0f);
    const float var = tsq * (1.0f / 128.0f) - mu * mu;
    muL[t] = mu;
    rsL[t] = rsqrtf(var + 1e-5f);
  }
  __syncthreads();

  // ---------------- normalize + residual + store + (edge) scatter-add (R2 verbatim) ----------------
#pragma unroll
  for (int rt = 0; rt < 4; ++rt) {
#pragma unroll
    for (int q = 0; q < 4; ++q) {
      const int rr = wr * 64 + rt * 16 + lg * 4 + q;
      const int grow = row0 + rr;
      if (grow < P.nRows) {
        const float mu = muL[rr], rs = rsL[rr];
        const float* rin = P.attrIn + (size_t)grow * LDIM;
        float* rout = P.attrOut + (size_t)grow * LDIM;
        float* ssum = nullptr;
        if (IS_EDGE) ssum = P.sum1 + (size_t)idxb[rr] * LDIM;
#pragma unroll
        for (int ct = 0; ct < 4; ++ct) {
          const int cc = wcc * 64 + ct * 16 + lr;
          const float o = gs[cc] * (acc2[rt][ct][q] - mu) * rs + bes[cc] + rin[cc];
          rout[cc] = o;
          if (IS_EDGE) atomicAdd(ssum + cc, o);
        }
      }
    }
  }
}

// ---- prep kernels ----
__global__ void prep_weights(const float* w1a, const float* w1b, const float* w1c,
                             const float* w2a, const float* w2b, const float* w2c,
                             short* w1h, short* w2h, short* w2l) {
  int i = blockIdx.x * 256 + threadIdx.x;
  constexpr int N1 = 18 * 128 * 384;
  constexpr int N2 = 18 * 128 * 128;
  if (i < N1) {
    int g = i / (128 * 384);
    int rem = i - g * (128 * 384);
    int n = rem / 384, k = rem - n * 384;
    int m = g / 6, s = g - m * 6;
    const float* src = (m == 0) ? w1a : (m == 1) ? w1b : w1c;
    w1h[i] = f2b(src[(size_t)s * (384 * 128) + (size_t)k * 128 + n]);
  } else if (i < N1 + N2) {
    int j = i - N1;
    int g = j / (128 * 128);
    int rem = j - g * (128 * 128);
    int n = rem / 128, k = rem - n * 128;
    int m = g / 6, s = g - m * 6;
    const float* src = (m == 0) ? w2a : (m == 1) ? w2b : w2c;
    float f = src[(size_t)s * (128 * 128) + (size_t)k * 128 + n];
    short hi = f2b(f);
    w2h[j] = hi;
    w2l[j] = f2b(f - b2f(hi));
  }
}

__global__ void prep_deg(const int* mr, const int* wrcv, int* degm, int* degw) {
  int i = blockIdx.x * 256 + threadIdx.x;
  if (i < EM_N) atomicAdd(&degm[mr[i]], 1);
  else if (i < EM_N + EW_N) atomicAdd(&degw[wrcv[i - EM_N]], 1);
}

__global__ void prep_inv(const int* degm, const int* degw, float* invm, float* invw) {
  int i = blockIdx.x * 256 + threadIdx.x;
  if (i < NNODE) {
    invm[i] = 1.0f / fmaxf((float)degm[i], 1.0f);
    invw[i] = 1.0f / fmaxf((float)degw[i], 1.0f);
  }
}

extern "C" void kernel_launch(void* const* d_in, const int* in_sizes, int n_in,
                              void* d_out, int out_size, void* d_ws, size_t ws_size,
                              hipStream_t stream) {
  (void)in_sizes; (void)n_in; (void)out_size; (void)ws_size;
  const float* x_in   = (const float*)d_in[0];
  const float* mea_in = (const float*)d_in[1];
  const float* wea_in = (const float*)d_in[2];
  const int*   mei    = (const int*)d_in[3];
  const int*   wei    = (const int*)d_in[4];
  const float* W1s[3] = { (const float*)d_in[5],  (const float*)d_in[11], (const float*)d_in[17] };
  const float* B1s[3] = { (const float*)d_in[6],  (const float*)d_in[12], (const float*)d_in[18] };
  const float* W2s[3] = { (const float*)d_in[7],  (const float*)d_in[13], (const float*)d_in[19] };
  const float* B2s[3] = { (const float*)d_in[8],  (const float*)d_in[14], (const float*)d_in[20] };
  const float* Gs[3]  = { (const float*)d_in[9],  (const float*)d_in[15], (const float*)d_in[21] };
  const float* Be[3]  = { (const float*)d_in[10], (const float*)d_in[16], (const float*)d_in[22] };

  float* xo  = (float*)d_out;
  float* meo = xo  + (size_t)NNODE * LDIM;
  float* weo = meo + (size_t)EM_N * LDIM;

  float* msum = (float*)d_ws;
  float* wsum = msum + (size_t)NNODE * LDIM;
  int*   degm = (int*)(wsum + (size_t)NNODE * LDIM);
  int*   degw = degm + NNODE;
  float* invm = (float*)(degw + NNODE);
  float* invw = invm + NNODE;
  short* w1h  = (short*)(invw + NNODE);
  short* w2h  = w1h + (size_t)18 * 128 * 384;
  short* w2l  = w2h + (size_t)18 * 128 * 128;

  size_t zbytes = (size_t)2 * NNODE * LDIM * 4 + (size_t)2 * NNODE * 4;
  hipMemsetAsync(d_ws, 0, zbytes, stream);

  {
    int tot = 18 * 128 * 384 + 18 * 128 * 128;
    prep_weights<<<dim3((tot + 255) / 256), 256, 0, stream>>>(
        W1s[0], W1s[1], W1s[2], W2s[0], W2s[1], W2s[2], w1h, w2h, w2l);
  }
  prep_deg<<<dim3((EM_N + EW_N + 255) / 256), 256, 0, stream>>>(mei + EM_N, wei + EW_N, degm, degw);
  prep_inv<<<dim3((NNODE + 255) / 256), 256, 0, stream>>>(degm, degw, invm, invw);

  const int MB = (EM_N + 127) / 128;   // 782
  const int WB = (EW_N + 127) / 128;   // 196
  const int NB = (NNODE + 127) / 128;  // 157

  const float* xc = x_in;
  const float* mc = mea_in;
  const float* wc = wea_in;

  for (int s = 0; s < NSTEP; ++s) {
    MlpParams pm{}, pw{}, pn{};

    pm.x = xc; pm.attrIn = mc; pm.attrOut = meo;
    pm.src = mei; pm.dst = mei + EM_N;
    pm.sum1 = msum;
    pm.W1H = w1h + (size_t)(0 * 6 + s) * 128 * 384;
    pm.W2H = w2h + (size_t)(0 * 6 + s) * 128 * 128;
    pm.W2L = w2l + (size_t)(0 * 6 + s) * 128 * 128;
    pm.b1 = B1s[0] + s * LDIM; pm.b2 = B2s[0] + s * LDIM;
    pm.gam = Gs[0] + s * LDIM; pm.bet = Be[0] + s * LDIM;
    pm.nRows = EM_N;

    pw.x = xc; pw.attrIn = wc; pw.attrOut = weo;
    pw.src = wei; pw.dst = wei + EW_N;
    pw.sum1 = wsum;
    pw.W1H = w1h + (size_t)(1 * 6 + s) * 128 * 384;
    pw.W2H = w2h + (size_t)(1 * 6 + s) * 128 * 128;
    pw.W2L = w2l + (size_t)(1 * 6 + s) * 128 * 128;
    pw.b1 = B1s[1] + s * LDIM; pw.b2 = B2s[1] + s * LDIM;
    pw.gam = Gs[1] + s * LDIM; pw.bet = Be[1] + s * LDIM;
    pw.nRows = EW_N;

    mlp_kernel<true><<<dim3(MB + WB), 256, 0, stream>>>(pm, pw, MB);

    pn.x = xc; pn.attrIn = xc; pn.attrOut = xo;
    pn.sum1 = msum; pn.sum2 = wsum; pn.inv1 = invm; pn.inv2 = invw;
    pn.W1H = w1h + (size_t)(2 * 6 + s) * 128 * 384;
    pn.W2H = w2h + (size_t)(2 * 6 + s) * 128 * 128;
    pn.W2L = w2l + (size_t)(2 * 6 + s) * 128 * 128;
    pn.b1 = B1s[2] + s * LDIM; pn.b2 = B2s[2] + s * LDIM;
    pn.gam = Gs[2] + s * LDIM; pn.bet = Be[2] + s * LDIM;
    pn.nRows = NNODE;

    mlp_kernel<false><<<dim3(NB), 256, 0, stream>>>(pn, pn, NB);

    xc = xo; mc = meo; wc = weo;
  }
}